// Round 6
// baseline (520.502 us; speedup 1.0000x reference)
//
#include <hip/hip_runtime.h>
#include <math.h>

#define BB   32
#define TT   1024
#define VV   1024
#define LM   128
#define SS   257
#define SP   272        // floats per row = 1088 B = 17 full cache lines
#define NCH  128        // chunks per batch (8 rows each)

// d_ws layout: [0, 16 KB) int flags[32][128]; [64 KB, ...) float lp[B][TT][SP]

// ---- DP macros (f64 alpha: a0..a3 = states 4l..4l+3, a4 = state 256 @lane63)

#define ONE_STEP(u) do {                                                       \
    double n1_ = __shfl_up(a3, 1); if (lane == 0) n1_ = 0.0;                   \
    const double t0_ = (a0 + n1_) * (double)(u).x;                             \
    const double t1_ = (a1 + a0 + (skip1 ? n1_ : 0.0)) * (double)(u).y;        \
    const double t2_ = (a2 + a1) * (double)(u).z;                              \
    const double t3_ = (a3 + a2 + (skip3 ? a1 : 0.0)) * (double)(u).w;         \
    const double t4_ = (a4 + a3) * (double)(u).x;                              \
    a0 = t0_; a1 = t1_; a2 = t2_; a3 = t3_; a4 = (lane == 63) ? t4_ : 0.0;     \
} while (0)

// two steps fused: 3 PARALLEL shfls; neighbor b_{4l-1} rebuilt locally from
// n1,n2,n3 and uw_n = neighbor's q.w (hoisted shfl, off the critical chain).
#define TWO_STEP(u, uwn, v) do {                                               \
    double n1_ = __shfl_up(a3, 1);                                             \
    double n2_ = __shfl_up(a2, 1);                                             \
    double n3_ = __shfl_up(a1, 1);                                             \
    if (lane == 0) { n1_ = 0.0; n2_ = 0.0; n3_ = 0.0; }                        \
    const double b0_ = (a0 + n1_) * (double)(u).x;                             \
    const double b1_ = (a1 + a0 + (skip1 ? n1_ : 0.0)) * (double)(u).y;        \
    const double b2_ = (a2 + a1) * (double)(u).z;                              \
    const double b3_ = (a3 + a2 + (skip3 ? a1 : 0.0)) * (double)(u).w;         \
    const double b4_ = (a4 + a3) * (double)(u).x;                              \
    const double bn_ = (n1_ + n2_ + (skipn ? n3_ : 0.0)) * (double)(uwn);      \
    const double c0_ = (b0_ + bn_) * (double)(v).x;                            \
    const double c1_ = (b1_ + b0_ + (skip1 ? bn_ : 0.0)) * (double)(v).y;      \
    const double c2_ = (b2_ + b1_) * (double)(v).z;                            \
    const double c3_ = (b3_ + b2_ + (skip3 ? b1_ : 0.0)) * (double)(v).w;      \
    const double c4_ = (b4_ + b3_) * (double)(v).x;                            \
    a0 = c0_; a1 = c1_; a2 = c2_; a3 = c3_; a4 = (lane == 63) ? c4_ : 0.0;     \
} while (0)

#define PAIR(u, uwn, v, t_) do {                                               \
    if ((t_) + 1 < hl)      TWO_STEP(u, uwn, v);                               \
    else if ((t_) < hl)     ONE_STEP(u);                                       \
} while (0)

#define PROCESS(QQ, UN, c_) do {                                               \
    const int tb_ = (c_) * 8;                                                  \
    if ((c_) == 0) {                                                           \
        ONE_STEP(QQ[1]);                                                       \
        PAIR(QQ[2], UN[2], QQ[3], 2);                                          \
        PAIR(QQ[4], UN[4], QQ[5], 4);                                          \
        PAIR(QQ[6], UN[6], QQ[7], 6);                                          \
    } else {                                                                   \
        PAIR(QQ[0], UN[0], QQ[1], tb_);                                        \
        PAIR(QQ[2], UN[2], QQ[3], tb_ + 2);                                    \
        PAIR(QQ[4], UN[4], QQ[5], tb_ + 4);                                    \
        PAIR(QQ[6], UN[6], QQ[7], tb_ + 6);                                    \
    }                                                                          \
} while (0)

#define LOADCH(QQ, c_) do {                                                    \
    _Pragma("unroll")                                                          \
    for (int r_ = 0; r_ < 8; ++r_)                                             \
        QQ[r_] = *(const float4*)(lp + ((size_t)(c_) * 8 + r_) * SP + 4 * lane); \
} while (0)

#define NEIGH(QQ, UN) do {                                                     \
    _Pragma("unroll")                                                          \
    for (int r_ = 0; r_ < 8; ++r_) UN[r_] = __shfl_up(QQ[r_].w, 1);            \
} while (0)

#define RENORM() do {                                                          \
    double m_ = fmax(fmax(fmax(a0, a1), fmax(a2, a3)), a4);                    \
    _Pragma("unroll")                                                          \
    for (int o_ = 32; o_; o_ >>= 1) m_ = fmax(m_, __shfl_xor(m_, o_));         \
    const double inv_ = 1.0 / m_;                                              \
    a0 *= inv_; a1 *= inv_; a2 *= inv_; a3 *= inv_; a4 *= inv_;                \
    clog += log(m_);                                                           \
} while (0)

#define POLL(f_) do {                                                          \
    while (atomicAdd((int*)&(f_), 0) == 0) __builtin_amdgcn_s_sleep(4);        \
} while (0)

// producer row step (round-5 verified): fused online-softmax butterfly,
// center = row max -> p = exp(x - mx) <= 1; slot257 = log(sum) = LSE - mx.
#define ROW_STEP(C0, C1, C2, C3, N0, N1, N2, N3)                               \
    {                                                                          \
        if (i + 1 < nrows) {                                                   \
            const float4* nx = (const float4*)(xr + (size_t)(i + 1) * VV);     \
            N0 = nx[lane]; N1 = nx[lane + 64];                                 \
            N2 = nx[lane + 128]; N3 = nx[lane + 192];                          \
        }                                                                      \
        float4* sw = (float4*)srow;                                            \
        sw[lane] = C0; sw[lane + 64] = C1;                                     \
        sw[lane + 128] = C2; sw[lane + 192] = C3;                              \
        float m = fmaxf(fmaxf(fmaxf(C0.x, C0.y), fmaxf(C0.z, C0.w)),          \
                        fmaxf(fmaxf(C1.x, C1.y), fmaxf(C1.z, C1.w)));          \
        m = fmaxf(m, fmaxf(fmaxf(fmaxf(C2.x, C2.y), fmaxf(C2.z, C2.w)),       \
                           fmaxf(fmaxf(C3.x, C3.y), fmaxf(C3.z, C3.w))));      \
        float s = __expf(C0.x - m) + __expf(C0.y - m) + __expf(C0.z - m) +     \
                  __expf(C0.w - m) + __expf(C1.x - m) + __expf(C1.y - m) +     \
                  __expf(C1.z - m) + __expf(C1.w - m) + __expf(C2.x - m) +     \
                  __expf(C2.y - m) + __expf(C2.z - m) + __expf(C2.w - m) +     \
                  __expf(C3.x - m) + __expf(C3.y - m) + __expf(C3.z - m) +     \
                  __expf(C3.w - m);                                            \
        _Pragma("unroll")                                                      \
        for (int off = 32; off; off >>= 1) {                                   \
            const float mo = __shfl_xor(m, off);                               \
            const float so = __shfl_xor(s, off);                               \
            const float mn = fmaxf(m, mo);                                     \
            s = s * __expf(m - mn) + so * __expf(mo - mn);                     \
            m = mn;                                                            \
        }                                                                      \
        const float xbv = srow[0];                                             \
        const float x1v = srow[lab0];                                          \
        const float x3v = srow[lab1];                                          \
        const float pb  = __expf(xbv - m);                                     \
        ((float4*)(lpo + (size_t)i * SP))[lane] =                              \
            make_float4(pb, __expf(x1v - m), pb, __expf(x3v - m));             \
        if (lane < 16) {                                                       \
            float val = 0.f;                                                   \
            if (lane == 0) val = pb;                                           \
            if (lane == 1) val = __logf(s);                                    \
            lpo[(size_t)i * SP + 256 + lane] = val;                            \
        }                                                                      \
    }

__global__ __launch_bounds__(64) void ctc_fused_kernel(
    const float* __restrict__ ys_hat, const int* __restrict__ ys_pad,
    const int* __restrict__ hlens, const int* __restrict__ ys_lens,
    float* __restrict__ lp_all, int* __restrict__ flags,
    float* __restrict__ out)
{
    __shared__ float srow[VV];
    const int lane = threadIdx.x;

    if (blockIdx.x >= BB) {
        // ------------------------ PRODUCER: one wave, 8 contiguous rows ----
        const int gw = blockIdx.x - BB;
        const int b  = gw & 31;            // interleaved: chunk 0 of every
        const int ch = gw >> 5;            // batch is produced first
        const int t0 = ch * 8;
        const int hl = hlens[b];
        int nrows = hl - t0;
        if (nrows <= 0) return;
        if (nrows > 8) nrows = 8;

        const int lab0 = ys_pad[b * LM + 2 * lane];
        const int lab1 = ys_pad[b * LM + 2 * lane + 1];
        const float* xr  = ys_hat + ((size_t)b * TT + t0) * VV;
        float*       lpo = lp_all + ((size_t)b * TT + t0) * SP;

        float4 va0, va1, va2, va3, vb0, vb1, vb2, vb3;
        {
            const float4* cx = (const float4*)xr;
            va0 = cx[lane]; va1 = cx[lane + 64];
            va2 = cx[lane + 128]; va3 = cx[lane + 192];
        }
        int i = 0;
        for (;;) {
            ROW_STEP(va0, va1, va2, va3, vb0, vb1, vb2, vb3)
            if (++i >= nrows) break;
            ROW_STEP(vb0, vb1, vb2, vb3, va0, va1, va2, va3)
            if (++i >= nrows) break;
        }
        __threadfence();                        // L2 writeback (cross-XCD vis)
        atomicExch(&flags[b * NCH + ch], 1);    // publish chunk
        return;
    }

    // ---------------------------- CONSUMER: one wave per batch, f64 DP ----
    const int b  = blockIdx.x;
    const int hl = hlens[b];
    const int nch = (hl + 7) >> 3;
    const float* lp = lp_all + (size_t)b * TT * SP;
    const int* lab = ys_pad + b * LM;

    const bool skip1 = (lane > 0) && (lab[2 * lane] != lab[2 * lane - 1]);
    const bool skip3 = (lab[2 * lane + 1] != lab[2 * lane]);
    const bool skipn = __shfl_up((int)skip3, 1) != 0;   // skip of state 4l-1

    float4 qa[8], qb[8];
    float  una[8], unb[8];
    double clog = 0.0;

    POLL(flags[b * NCH + 0]);
    LOADCH(qa, 0);
    NEIGH(qa, una);                                     // forces vmcnt wait

    double a0 = (lane == 0) ? (double)qa[0].x : 0.0;    // t=0: states 0,1
    double a1 = (lane == 0) ? (double)qa[0].y : 0.0;
    double a2 = 0.0, a3 = 0.0, a4 = 0.0;

    for (int c = 0;; ++c) {
        const bool last = (c + 1 >= nch);
        if (!last) {                                    // overlap poll+load
            POLL(flags[b * NCH + c + 1]);
            if (c & 1) LOADCH(qa, c + 1);
            else       LOADCH(qb, c + 1);
        }
        if (c && !(c & 3)) RENORM();                    // every 32 steps
        if (c & 1) PROCESS(qb, unb, c);
        else       PROCESS(qa, una, c);
        if (last) break;
        if (c & 1) NEIGH(qa, una);
        else       NEIGH(qb, unb);
    }

    // sum of (LSE_t - mx_t): all rows published by now, off critical path
    float ssf = 0.f;
    for (int t = lane; t < hl; t += 64) ssf += lp[(size_t)t * SP + 257];
    #pragma unroll
    for (int off = 32; off; off >>= 1) ssf += __shfl_xor(ssf, off);

    // terminal states via shfl (no LDS, no barrier)
    const int L  = ys_lens[b];
    const int sA = 2 * L;                               // even
    const int sB = 2 * L - 1;                           // odd
    double vA;
    if (sA == 256) vA = __shfl(a4, 63);
    else vA = (sA & 2) ? __shfl(a2, sA >> 2) : __shfl(a0, sA >> 2);
    const double vB = (sB & 2) ? __shfl(a3, sB >> 2) : __shfl(a1, sB >> 2);

    if (lane == 0) {
        const double loss = (double)ssf - (log(vA + vB) + clog);
        atomicAdd(out, (float)(loss * (1.0 / (double)BB)));
    }
}

extern "C" void kernel_launch(void* const* d_in, const int* in_sizes, int n_in,
                              void* d_out, int out_size, void* d_ws, size_t ws_size,
                              hipStream_t stream) {
    const float* ys_hat  = (const float*)d_in[0];
    const int*   ys_pad  = (const int*)d_in[1];
    const int*   hlens   = (const int*)d_in[2];
    const int*   ys_lens = (const int*)d_in[3];
    float* out = (float*)d_out;

    int*   flags  = (int*)d_ws;                         // [32][128]
    float* lp_raw = (float*)((char*)d_ws + 65536);      // [B][TT][SP]

    hipMemsetAsync(d_out, 0, sizeof(float), stream);
    hipMemsetAsync(d_ws, 0, 16384, stream);             // zero flags

    ctc_fused_kernel<<<BB + BB * NCH, 64, 0, stream>>>(
        ys_hat, ys_pad, hlens, ys_lens, lp_raw, flags, out);
}

// Round 7
// 501.133 us; speedup vs baseline: 1.0387x; 1.0387x over previous
//
#include <hip/hip_runtime.h>
#include <math.h>

#define BB   32
#define TT   1024
#define VV   1024
#define LM   128
#define SS   257
#define SP   272        // floats per row = 1088 B = 17 full cache lines
#define NCH  128        // chunks per batch (8 rows each)
#define FST  4          // flag stride in ints (16 B) -> 4 chunks per line

// d_ws layout: [0, 64 KB) int flags[32][128][FST]; [64 KB, ...) float lp[B][TT][SP]
#define FLAG(b_, c_) flags[((b_) * NCH + (c_)) * FST]

// ---- DP macros (f64 alpha: a0..a3 = states 4l..4l+3, a4 = state 256 @lane63)

#define ONE_STEP(u) do {                                                       \
    double n1_ = __shfl_up(a3, 1); if (lane == 0) n1_ = 0.0;                   \
    const double t0_ = (a0 + n1_) * (double)(u).x;                             \
    const double t1_ = (a1 + a0 + (skip1 ? n1_ : 0.0)) * (double)(u).y;        \
    const double t2_ = (a2 + a1) * (double)(u).z;                              \
    const double t3_ = (a3 + a2 + (skip3 ? a1 : 0.0)) * (double)(u).w;         \
    const double t4_ = (a4 + a3) * (double)(u).x;                              \
    a0 = t0_; a1 = t1_; a2 = t2_; a3 = t3_; a4 = (lane == 63) ? t4_ : 0.0;     \
} while (0)

// two steps fused: 3 PARALLEL shfls; neighbor b_{4l-1} rebuilt locally from
// n1,n2,n3 and uw_n = neighbor's q.w (hoisted shfl, off the critical chain).
#define TWO_STEP(u, uwn, v) do {                                               \
    double n1_ = __shfl_up(a3, 1);                                             \
    double n2_ = __shfl_up(a2, 1);                                             \
    double n3_ = __shfl_up(a1, 1);                                             \
    if (lane == 0) { n1_ = 0.0; n2_ = 0.0; n3_ = 0.0; }                        \
    const double b0_ = (a0 + n1_) * (double)(u).x;                             \
    const double b1_ = (a1 + a0 + (skip1 ? n1_ : 0.0)) * (double)(u).y;        \
    const double b2_ = (a2 + a1) * (double)(u).z;                              \
    const double b3_ = (a3 + a2 + (skip3 ? a1 : 0.0)) * (double)(u).w;         \
    const double b4_ = (a4 + a3) * (double)(u).x;                              \
    const double bn_ = (n1_ + n2_ + (skipn ? n3_ : 0.0)) * (double)(uwn);      \
    const double c0_ = (b0_ + bn_) * (double)(v).x;                            \
    const double c1_ = (b1_ + b0_ + (skip1 ? bn_ : 0.0)) * (double)(v).y;      \
    const double c2_ = (b2_ + b1_) * (double)(v).z;                            \
    const double c3_ = (b3_ + b2_ + (skip3 ? b1_ : 0.0)) * (double)(v).w;      \
    const double c4_ = (b4_ + b3_) * (double)(v).x;                            \
    a0 = c0_; a1 = c1_; a2 = c2_; a3 = c3_; a4 = (lane == 63) ? c4_ : 0.0;     \
} while (0)

#define PAIR(u, uwn, v, t_) do {                                               \
    if ((t_) + 1 < hl)      TWO_STEP(u, uwn, v);                               \
    else if ((t_) < hl)     ONE_STEP(u);                                       \
} while (0)

#define PROCESS(QQ, UN, c_) do {                                               \
    const int tb_ = (c_) * 8;                                                  \
    if ((c_) == 0) {                                                           \
        ONE_STEP(QQ[1]);                                                       \
        PAIR(QQ[2], UN[2], QQ[3], 2);                                          \
        PAIR(QQ[4], UN[4], QQ[5], 4);                                          \
        PAIR(QQ[6], UN[6], QQ[7], 6);                                          \
    } else {                                                                   \
        PAIR(QQ[0], UN[0], QQ[1], tb_);                                        \
        PAIR(QQ[2], UN[2], QQ[3], tb_ + 2);                                    \
        PAIR(QQ[4], UN[4], QQ[5], tb_ + 4);                                    \
        PAIR(QQ[6], UN[6], QQ[7], tb_ + 6);                                    \
    }                                                                          \
} while (0)

#define LOADCH(QQ, c_) do {                                                    \
    _Pragma("unroll")                                                          \
    for (int r_ = 0; r_ < 8; ++r_)                                             \
        QQ[r_] = *(const float4*)(lp + ((size_t)(c_) * 8 + r_) * SP + 4 * lane); \
} while (0)

#define NEIGH(QQ, UN) do {                                                     \
    _Pragma("unroll")                                                          \
    for (int r_ = 0; r_ < 8; ++r_) UN[r_] = __shfl_up(QQ[r_].w, 1);            \
} while (0)

#define RENORM() do {                                                          \
    double m_ = fmax(fmax(fmax(a0, a1), fmax(a2, a3)), a4);                    \
    _Pragma("unroll")                                                          \
    for (int o_ = 32; o_; o_ >>= 1) m_ = fmax(m_, __shfl_xor(m_, o_));         \
    const double inv_ = 1.0 / m_;                                              \
    a0 *= inv_; a1 *= inv_; a2 *= inv_; a3 *= inv_; a4 *= inv_;                \
    clog += log(m_);                                                           \
} while (0)

// SINGLE-LANE blocking poll (round 6 ran this on all 64 lanes -> 64 serialized
// same-address RMWs per iteration, the whole regression). Wave reconverges
// after the masked loop, so lanes 1..63 simply wait.
#define POLLW(addr_) do {                                                      \
    if (lane == 0) {                                                           \
        while (atomicAdd((addr_), 0) == 0) __builtin_amdgcn_s_sleep(2);        \
    }                                                                          \
} while (0)

// producer row step (round-5 verified): fused online-softmax butterfly,
// center = row max -> p = exp(x - mx) <= 1; slot257 = log(sum) = LSE - mx.
#define ROW_STEP(C0, C1, C2, C3, N0, N1, N2, N3)                               \
    {                                                                          \
        if (i + 1 < nrows) {                                                   \
            const float4* nx = (const float4*)(xr + (size_t)(i + 1) * VV);     \
            N0 = nx[lane]; N1 = nx[lane + 64];                                 \
            N2 = nx[lane + 128]; N3 = nx[lane + 192];                          \
        }                                                                      \
        float4* sw = (float4*)srow;                                            \
        sw[lane] = C0; sw[lane + 64] = C1;                                     \
        sw[lane + 128] = C2; sw[lane + 192] = C3;                              \
        float m = fmaxf(fmaxf(fmaxf(C0.x, C0.y), fmaxf(C0.z, C0.w)),          \
                        fmaxf(fmaxf(C1.x, C1.y), fmaxf(C1.z, C1.w)));          \
        m = fmaxf(m, fmaxf(fmaxf(fmaxf(C2.x, C2.y), fmaxf(C2.z, C2.w)),       \
                           fmaxf(fmaxf(C3.x, C3.y), fmaxf(C3.z, C3.w))));      \
        float s = __expf(C0.x - m) + __expf(C0.y - m) + __expf(C0.z - m) +     \
                  __expf(C0.w - m) + __expf(C1.x - m) + __expf(C1.y - m) +     \
                  __expf(C1.z - m) + __expf(C1.w - m) + __expf(C2.x - m) +     \
                  __expf(C2.y - m) + __expf(C2.z - m) + __expf(C2.w - m) +     \
                  __expf(C3.x - m) + __expf(C3.y - m) + __expf(C3.z - m) +     \
                  __expf(C3.w - m);                                            \
        _Pragma("unroll")                                                      \
        for (int off = 32; off; off >>= 1) {                                   \
            const float mo = __shfl_xor(m, off);                               \
            const float so = __shfl_xor(s, off);                               \
            const float mn = fmaxf(m, mo);                                     \
            s = s * __expf(m - mn) + so * __expf(mo - mn);                     \
            m = mn;                                                            \
        }                                                                      \
        const float xbv = srow[0];                                             \
        const float x1v = srow[lab0];                                          \
        const float x3v = srow[lab1];                                          \
        const float pb  = __expf(xbv - m);                                     \
        ((float4*)(lpo + (size_t)i * SP))[lane] =                              \
            make_float4(pb, __expf(x1v - m), pb, __expf(x3v - m));             \
        if (lane < 16) {                                                       \
            float val = 0.f;                                                   \
            if (lane == 0) val = pb;                                           \
            if (lane == 1) val = __logf(s);                                    \
            lpo[(size_t)i * SP + 256 + lane] = val;                            \
        }                                                                      \
    }

__global__ __launch_bounds__(64) void ctc_fused_kernel(
    const float* __restrict__ ys_hat, const int* __restrict__ ys_pad,
    const int* __restrict__ hlens, const int* __restrict__ ys_lens,
    float* __restrict__ lp_all, int* __restrict__ flags,
    float* __restrict__ out)
{
    __shared__ float srow[VV];
    const int lane = threadIdx.x;

    if (blockIdx.x >= BB) {
        // ------------------------ PRODUCER: one wave, 8 contiguous rows ----
        const int gw = blockIdx.x - BB;
        const int b  = gw & 31;            // interleaved: chunk 0 of every
        const int ch = gw >> 5;            // batch is produced first
        const int t0 = ch * 8;
        const int hl = hlens[b];
        int nrows = hl - t0;
        if (nrows <= 0) return;
        if (nrows > 8) nrows = 8;

        const int lab0 = ys_pad[b * LM + 2 * lane];
        const int lab1 = ys_pad[b * LM + 2 * lane + 1];
        const float* xr  = ys_hat + ((size_t)b * TT + t0) * VV;
        float*       lpo = lp_all + ((size_t)b * TT + t0) * SP;

        float4 va0, va1, va2, va3, vb0, vb1, vb2, vb3;
        {
            const float4* cx = (const float4*)xr;
            va0 = cx[lane]; va1 = cx[lane + 64];
            va2 = cx[lane + 128]; va3 = cx[lane + 192];
        }
        int i = 0;
        for (;;) {
            ROW_STEP(va0, va1, va2, va3, vb0, vb1, vb2, vb3)
            if (++i >= nrows) break;
            ROW_STEP(vb0, vb1, vb2, vb3, va0, va1, va2, va3)
            if (++i >= nrows) break;
        }
        __threadfence();                          // release: rows -> coherent
        if (lane == 0) atomicExch(&FLAG(b, ch), 1);   // single-lane publish
        return;
    }

    // ---------------------------- CONSUMER: one wave per batch, f64 DP ----
    const int b  = blockIdx.x;
    const int hl = hlens[b];
    const int nch = (hl + 7) >> 3;
    const float* lp = lp_all + (size_t)b * TT * SP;
    const int* lab = ys_pad + b * LM;

    const bool skip1 = (lane > 0) && (lab[2 * lane] != lab[2 * lane - 1]);
    const bool skip3 = (lab[2 * lane + 1] != lab[2 * lane]);
    const bool skipn = __shfl_up((int)skip3, 1) != 0;   // skip of state 4l-1

    float4 qa[8], qb[8];
    float  una[8], unb[8];
    double clog = 0.0;

    POLLW(&FLAG(b, 0));
    LOADCH(qa, 0);
    NEIGH(qa, una);                                     // forces vmcnt wait

    double a0 = (lane == 0) ? (double)qa[0].x : 0.0;    // t=0: states 0,1
    double a1 = (lane == 0) ? (double)qa[0].y : 0.0;
    double a2 = 0.0, a3 = 0.0, a4 = 0.0;

    if (nch > 1) POLLW(&FLAG(b, 1));                    // flag for chunk 1

    for (int c = 0;; ++c) {
        const bool last = (c + 1 >= nch);
        int fpre = 1;
        if (!last) {
            // flag for chunk c+1 was confirmed on the previous iteration
            if (c & 1) LOADCH(qa, c + 1);
            else       LOADCH(qb, c + 1);
            // issue the c+2 flag RMW now; its ~500cyc round-trip overlaps
            // PROCESS below (pure VALU/DS). Checked after.
            if (c + 2 < nch && lane == 0) fpre = atomicAdd(&FLAG(b, c + 2), 0);
        }
        if (c && !(c & 3)) RENORM();                    // every 32 steps
        if (c & 1) PROCESS(qb, unb, c);
        else       PROCESS(qa, una, c);
        if (last) break;
        if (c + 2 < nch) {
            fpre = __shfl(fpre, 0);
            if (fpre == 0) POLLW(&FLAG(b, c + 2));      // rare: producer behind
        }
        if (c & 1) NEIGH(qa, una);
        else       NEIGH(qb, unb);
    }

    // sum of (LSE_t - mx_t): all rows published by now, off critical path
    float ssf = 0.f;
    for (int t = lane; t < hl; t += 64) ssf += lp[(size_t)t * SP + 257];
    #pragma unroll
    for (int off = 32; off; off >>= 1) ssf += __shfl_xor(ssf, off);

    // terminal states via shfl (no LDS, no barrier)
    const int L  = ys_lens[b];
    const int sA = 2 * L;                               // even
    const int sB = 2 * L - 1;                           // odd
    double vA;
    if (sA == 256) vA = __shfl(a4, 63);
    else vA = (sA & 2) ? __shfl(a2, sA >> 2) : __shfl(a0, sA >> 2);
    const double vB = (sB & 2) ? __shfl(a3, sB >> 2) : __shfl(a1, sB >> 2);

    if (lane == 0) {
        const double loss = (double)ssf - (log(vA + vB) + clog);
        atomicAdd(out, (float)(loss * (1.0 / (double)BB)));
    }
}

extern "C" void kernel_launch(void* const* d_in, const int* in_sizes, int n_in,
                              void* d_out, int out_size, void* d_ws, size_t ws_size,
                              hipStream_t stream) {
    const float* ys_hat  = (const float*)d_in[0];
    const int*   ys_pad  = (const int*)d_in[1];
    const int*   hlens   = (const int*)d_in[2];
    const int*   ys_lens = (const int*)d_in[3];
    float* out = (float*)d_out;

    int*   flags  = (int*)d_ws;                         // [32][128][FST] = 64 KB
    float* lp_raw = (float*)((char*)d_ws + 65536);      // [B][TT][SP]

    hipMemsetAsync(d_out, 0, sizeof(float), stream);
    hipMemsetAsync(d_ws, 0, 65536, stream);             // zero flags

    ctc_fused_kernel<<<BB + BB * NCH, 64, 0, stream>>>(
        ys_hat, ys_pad, hlens, ys_lens, lp_raw, flags, out);
}